// Round 1
// baseline (676.936 us; speedup 1.0000x reference)
//
#include <hip/hip_runtime.h>
#include <cfloat>
#include <cstdint>

// ---------------------------------------------------------------------------
// AttentionPool: LN(q) @ Wq ; kv @ Wkv -> K,V ; per-head RMSNorm(Q,K);
// masked softmax(Q K^T) V ; out @ Wout.   B=8, Nq=128, Nkv=4096, H=16, D=64.
// All matmuls in fp16 MFMA (16x16x32) with fp32 accumulate.
// ---------------------------------------------------------------------------

typedef _Float16 f16;
typedef _Float16 f16x8 __attribute__((ext_vector_type(8)));
typedef _Float16 f16x4 __attribute__((ext_vector_type(4)));
typedef float    f32x4 __attribute__((ext_vector_type(4)));

#define DEV __device__ __forceinline__

DEV f32x4 mfma16(f16x8 a, f16x8 b, f32x4 c) {
  return __builtin_amdgcn_mfma_f32_16x16x32_f16(a, b, c, 0, 0, 0);
}

DEV void gl_lds16(const void* g, void* l) {
  __builtin_amdgcn_global_load_lds(
      (const __attribute__((address_space(1))) uint32_t*)g,
      (__attribute__((address_space(3))) uint32_t*)l, 16, 0, 0);
}

// --------------------------- elementwise kernels ---------------------------

__global__ __launch_bounds__(256) void cast_f16_kernel(
    const float* __restrict__ src, f16* __restrict__ dst, int n4) {
  int stride = gridDim.x * 256;
  for (int i = blockIdx.x * 256 + threadIdx.x; i < n4; i += stride) {
    float4 v = ((const float4*)src)[i];
    f16x4 o = { (f16)v.x, (f16)v.y, (f16)v.z, (f16)v.w };
    ((f16x4*)dst)[i] = o;
  }
}

// transpose fp32 [R][ldsrc] -> f16 [C][lddst]; R,C multiples of 32
__global__ __launch_bounds__(256) void transpose_cast_kernel(
    const float* __restrict__ src, f16* __restrict__ dst, int ldsrc, int lddst) {
  __shared__ float tile[32][33];
  int c0 = blockIdx.x * 32, r0 = blockIdx.y * 32;
  int tx = threadIdx.x & 31, ty = threadIdx.x >> 5;  // 32 x 8
  #pragma unroll
  for (int i = 0; i < 4; ++i)
    tile[ty + i * 8][tx] = src[(long)(r0 + ty + i * 8) * ldsrc + c0 + tx];
  __syncthreads();
  #pragma unroll
  for (int i = 0; i < 4; ++i)
    dst[(long)(c0 + ty + i * 8) * lddst + r0 + tx] = (f16)tile[tx][ty + i * 8];
}

// LayerNorm over 1024, one block per row
__global__ __launch_bounds__(256) void ln_kernel(
    const float* __restrict__ q, const float* __restrict__ w, f16* __restrict__ qn) {
  int row = blockIdx.x, tid = threadIdx.x;
  float4 v = ((const float4*)(q + (long)row * 1024))[tid];
  float s1 = v.x + v.y + v.z + v.w;
  float s2 = v.x * v.x + v.y * v.y + v.z * v.z + v.w * v.w;
  #pragma unroll
  for (int off = 1; off < 64; off <<= 1) {
    s1 += __shfl_xor(s1, off);
    s2 += __shfl_xor(s2, off);
  }
  __shared__ float r1[4], r2[4];
  int wid = tid >> 6;
  if ((tid & 63) == 0) { r1[wid] = s1; r2[wid] = s2; }
  __syncthreads();
  s1 = r1[0] + r1[1] + r1[2] + r1[3];
  s2 = r2[0] + r2[1] + r2[2] + r2[3];
  float mu = s1 * (1.0f / 1024.0f);
  float var = s2 * (1.0f / 1024.0f) - mu * mu;
  float rstd = rsqrtf(var + 1e-5f);
  float4 wv = ((const float4*)w)[tid];
  f16x4 o = { (f16)((v.x - mu) * rstd * wv.x), (f16)((v.y - mu) * rstd * wv.y),
              (f16)((v.z - mu) * rstd * wv.z), (f16)((v.w - mu) * rstd * wv.w) };
  ((f16x4*)(qn + (long)row * 1024))[tid] = o;
}

// per-head RMSNorm in place: x / max(||x||,1e-12) * 8 * gamma. One wave per (row,head).
__global__ __launch_bounds__(256) void rmsnorm_kernel(
    f16* __restrict__ X, const float* __restrict__ gamma, int nrows, int ld) {
  int unit = blockIdx.x * 4 + (threadIdx.x >> 6);
  int lane = threadIdx.x & 63;
  if (unit >= nrows * 16) return;
  int r = unit >> 4, h = unit & 15;
  f16* p = X + (long)r * ld + h * 64;
  float x = (float)p[lane];
  float s = x * x;
  #pragma unroll
  for (int off = 1; off < 64; off <<= 1) s += __shfl_xor(s, off);
  float scale = 8.0f / fmaxf(sqrtf(s), 1e-12f);
  p[lane] = (f16)(x * scale * gamma[h * 64 + lane]);
}

// ------------------------------- GEMM (m97) --------------------------------
// C[M][N] = A[M][K] @ BT[N][K]^T, f16 in, fp32 accum, f16 or f32 out.
// 128x128 tile, BK=32, 4 waves (2x2), 4x4 16x16 frags per wave.
template <int OUT_F16>
__global__ __launch_bounds__(256) void gemm128(
    const f16* __restrict__ A, const f16* __restrict__ BT, void* __restrict__ C,
    int M, int N, int K, int lda, int ldb, int ldc) {
  __shared__ f16 tA[128 * 32];
  __shared__ f16 tB[128 * 32];
  const int tid = threadIdx.x, lane = tid & 63, wid = tid >> 6;
  const int wr = wid >> 1, wc = wid & 1;
  const int c = lane & 15, g = lane >> 4;
  const int m0 = blockIdx.y * 128, n0 = blockIdx.x * 128;
  f32x4 acc[4][4] = {};
  for (int k0 = 0; k0 < K; k0 += 32) {
    __syncthreads();
    #pragma unroll
    for (int ii = 0; ii < 2; ++ii) {
      int i = tid + ii * 256;
      gl_lds16(A + (long)(m0 + (i >> 2)) * lda + k0 + (i & 3) * 8, tA + i * 8);
    }
    #pragma unroll
    for (int ii = 0; ii < 2; ++ii) {
      int i = tid + ii * 256;
      gl_lds16(BT + (long)(n0 + (i >> 2)) * ldb + k0 + (i & 3) * 8, tB + i * 8);
    }
    __syncthreads();
    f16x8 af[4], bfr[4];
    #pragma unroll
    for (int mi = 0; mi < 4; ++mi)
      af[mi] = *(const f16x8*)&tA[(wr * 64 + mi * 16 + c) * 32 + g * 8];
    #pragma unroll
    for (int ni = 0; ni < 4; ++ni)
      bfr[ni] = *(const f16x8*)&tB[(wc * 64 + ni * 16 + c) * 32 + g * 8];
    #pragma unroll
    for (int mi = 0; mi < 4; ++mi)
      #pragma unroll
      for (int ni = 0; ni < 4; ++ni)
        acc[mi][ni] = mfma16(af[mi], bfr[ni], acc[mi][ni]);
  }
  #pragma unroll
  for (int mi = 0; mi < 4; ++mi)
    #pragma unroll
    for (int ni = 0; ni < 4; ++ni)
      #pragma unroll
      for (int j = 0; j < 4; ++j) {
        int row = m0 + wr * 64 + mi * 16 + g * 4 + j;
        int col = n0 + wc * 64 + ni * 16 + c;
        if (OUT_F16) ((f16*)C)[(long)row * ldc + col] = (f16)acc[mi][ni][j];
        else        ((float*)C)[(long)row * ldc + col] = acc[mi][ni][j];
      }
}

// ---------------------------- flash attention ------------------------------
// grid 256 = (b, h, half). 4 waves x 16 q-rows. KV tile = 64 rows.
// Q: [8*128][1024] f16 (rmsnormed), KV: [8*4096][2048] (cols 0..1023 = Kh, 1024.. = V)
__global__ __launch_bounds__(256) void attn_kernel(
    const f16* __restrict__ Q, const f16* __restrict__ KV,
    const int* __restrict__ mask, f16* __restrict__ O) {
  __shared__ f16 Kt[64 * 64];       // XOR-swizzled [kv][64]
  __shared__ f16 Vt[64 * 72];       // transposed [d][kv], stride 72 (16B aligned)
  __shared__ f16 Pl[4 * 16 * 72];   // per-wave P [16 q][64 kv], stride 72
  const int blk = blockIdx.x;
  const int half = blk & 1, h = (blk >> 1) & 15, b = blk >> 5;
  const int tid = threadIdx.x, lane = tid & 63, wid = tid >> 6;
  const int c = lane & 15, g = lane >> 4;

  // Q fragments (A-operand), hoisted: row = lane&15, k = (lane>>4)*8
  const int qrow = b * 128 + half * 64 + wid * 16 + c;
  f16x8 qa[2];
  #pragma unroll
  for (int kk = 0; kk < 2; ++kk)
    qa[kk] = *(const f16x8*)&Q[(long)qrow * 1024 + h * 64 + kk * 32 + g * 8];

  float m_[4], l_[4];
  f32x4 o_[4];
  #pragma unroll
  for (int j = 0; j < 4; ++j) { m_[j] = -FLT_MAX; l_[j] = 0.f; }
  #pragma unroll
  for (int ni = 0; ni < 4; ++ni) o_[ni] = (f32x4){0.f, 0.f, 0.f, 0.f};

  const long kvbase = (long)b * 4096 * 2048;
  f16* Pw = Pl + wid * 16 * 72;

  for (int kt = 0; kt < 64; ++kt) {
    __syncthreads();
    // stage K tile, XOR-swizzle via pre-swizzled global source column
    #pragma unroll
    for (int ii = 0; ii < 2; ++ii) {
      int i = tid + ii * 256;
      int r = i >> 3, s = i & 7;
      gl_lds16(KV + kvbase + (long)(kt * 64 + r) * 2048 + h * 64 + ((s ^ (r & 7)) * 8),
               Kt + i * 8);
    }
    // stage V transposed via registers (lane = kv -> conflict-free-ish scatter)
    #pragma unroll
    for (int ii = 0; ii < 2; ++ii) {
      int i = tid + ii * 256;
      int kv = i & 63, d0 = (i >> 6) * 8;
      f16x8 v = *(const f16x8*)&KV[kvbase + (long)(kt * 64 + kv) * 2048 + 1024 + h * 64 + d0];
      #pragma unroll
      for (int j = 0; j < 8; ++j) Vt[(d0 + j) * 72 + kv] = v[j];
    }
    __syncthreads();

    // S = Q K^T  (16 q x 64 kv per wave)
    f32x4 s4[4];
    #pragma unroll
    for (int ni = 0; ni < 4; ++ni) {
      s4[ni] = (f32x4){0.f, 0.f, 0.f, 0.f};
      int kvr = ni * 16 + c;
      #pragma unroll
      for (int kk = 0; kk < 2; ++kk) {
        int slot = (kk * 4 + g) ^ (kvr & 7);
        f16x8 kb = *(const f16x8*)&Kt[kvr * 64 + slot * 8];
        s4[ni] = mfma16(qa[kk], kb, s4[ni]);
      }
    }

    // mask (per lane: fixed kv column per ni)
    int msk[4];
    #pragma unroll
    for (int ni = 0; ni < 4; ++ni) {
      msk[ni] = mask[b * 4096 + kt * 64 + ni * 16 + c];
      if (!msk[ni]) s4[ni] = (f32x4){-FLT_MAX, -FLT_MAX, -FLT_MAX, -FLT_MAX};
    }

    // online softmax: row max (reduce across 16-lane group)
    float mnew[4], alpha[4], psum[4];
    #pragma unroll
    for (int j = 0; j < 4; ++j) {
      float v = fmaxf(fmaxf(s4[0][j], s4[1][j]), fmaxf(s4[2][j], s4[3][j]));
      v = fmaxf(v, __shfl_xor(v, 1));
      v = fmaxf(v, __shfl_xor(v, 2));
      v = fmaxf(v, __shfl_xor(v, 4));
      v = fmaxf(v, __shfl_xor(v, 8));
      mnew[j] = fmaxf(m_[j], v);
      alpha[j] = __expf(m_[j] - mnew[j]);
      m_[j] = mnew[j];
      psum[j] = 0.f;
    }
    f16 pb[4][4];
    #pragma unroll
    for (int ni = 0; ni < 4; ++ni)
      #pragma unroll
      for (int j = 0; j < 4; ++j) {
        float p = msk[ni] ? __expf(s4[ni][j] - mnew[j]) : 0.0f;
        psum[j] += p;
        pb[ni][j] = (f16)p;
      }
    #pragma unroll
    for (int j = 0; j < 4; ++j) {
      float ps = psum[j];
      ps += __shfl_xor(ps, 1);
      ps += __shfl_xor(ps, 2);
      ps += __shfl_xor(ps, 4);
      ps += __shfl_xor(ps, 8);
      l_[j] = alpha[j] * l_[j] + ps;
    }
    // P -> per-wave LDS (C-layout write, A-layout read)
    #pragma unroll
    for (int ni = 0; ni < 4; ++ni)
      #pragma unroll
      for (int j = 0; j < 4; ++j)
        Pw[(g * 4 + j) * 72 + ni * 16 + c] = pb[ni][j];
    // rescale O
    #pragma unroll
    for (int ni = 0; ni < 4; ++ni)
      #pragma unroll
      for (int j = 0; j < 4; ++j)
        o_[ni][j] *= alpha[j];
    // PV
    f16x8 pa[2];
    #pragma unroll
    for (int kk = 0; kk < 2; ++kk)
      pa[kk] = *(const f16x8*)&Pw[c * 72 + kk * 32 + g * 8];
    #pragma unroll
    for (int ni = 0; ni < 4; ++ni)
      #pragma unroll
      for (int kk = 0; kk < 2; ++kk) {
        f16x8 vb = *(const f16x8*)&Vt[(ni * 16 + c) * 72 + kk * 32 + g * 8];
        o_[ni] = mfma16(pa[kk], vb, o_[ni]);
      }
  }

  // epilogue: normalize and store O[b*128+q][h*64+d]
  #pragma unroll
  for (int j = 0; j < 4; ++j) {
    float inv = 1.0f / fmaxf(l_[j], 1e-30f);
    int row = b * 128 + half * 64 + wid * 16 + g * 4 + j;
    #pragma unroll
    for (int ni = 0; ni < 4; ++ni) {
      int col = h * 64 + ni * 16 + c;
      O[(long)row * 1024 + col] = (f16)(o_[ni][j] * inv);
    }
  }
}

// ------------------------------- launcher ----------------------------------

extern "C" void kernel_launch(void* const* d_in, const int* in_sizes, int n_in,
                              void* d_out, int out_size, void* d_ws, size_t ws_size,
                              hipStream_t stream) {
  const float* q    = (const float*)d_in[0];
  const float* kv   = (const float*)d_in[1];
  const int*   mask = (const int*)d_in[2];
  const float* ln_w = (const float*)d_in[3];
  const float* gq   = (const float*)d_in[4];
  const float* gk   = (const float*)d_in[5];
  const float* Wq   = (const float*)d_in[6];
  const float* Wkv  = (const float*)d_in[7];
  const float* Wout = (const float*)d_in[8];
  float* out = (float*)d_out;
  char* ws = (char*)d_ws;
  const size_t MB = (size_t)1 << 20;
  f16* qn    = (f16*)(ws + 0 * MB);    // 2 MB   [1024][1024]
  f16* Qm    = (f16*)(ws + 2 * MB);    // 2 MB   [1024][1024]
  f16* Om    = (f16*)(ws + 4 * MB);    // 2 MB   [1024][1024]
  f16* WqT   = (f16*)(ws + 6 * MB);    // 2 MB   [1024][1024]
  f16* WkvT  = (f16*)(ws + 8 * MB);    // 4 MB   [2048][1024]
  f16* WoutT = (f16*)(ws + 12 * MB);   // 2 MB   [1024][1024]
  f16* kv16  = (f16*)(ws + 14 * MB);   // 64 MB  [32768][1024]
  f16* KVp   = (f16*)(ws + 78 * MB);   // 128 MB [32768][2048]  (K normed in place)

  cast_f16_kernel<<<2048, 256, 0, stream>>>(kv, kv16, 8 * 4096 * 1024 / 4);
  transpose_cast_kernel<<<dim3(32, 32), 256, 0, stream>>>(Wq, WqT, 1024, 1024);
  transpose_cast_kernel<<<dim3(64, 32), 256, 0, stream>>>(Wkv, WkvT, 2048, 1024);
  transpose_cast_kernel<<<dim3(32, 32), 256, 0, stream>>>(Wout, WoutT, 1024, 1024);
  ln_kernel<<<1024, 256, 0, stream>>>(q, ln_w, qn);
  gemm128<1><<<dim3(8, 8), 256, 0, stream>>>(qn, WqT, Qm, 1024, 1024, 1024, 1024, 1024, 1024);
  gemm128<1><<<dim3(16, 256), 256, 0, stream>>>(kv16, WkvT, KVp, 32768, 2048, 1024, 1024, 1024, 2048);
  rmsnorm_kernel<<<(1024 * 16) / 4, 256, 0, stream>>>(Qm, gq, 1024, 1024);
  rmsnorm_kernel<<<(32768 * 16) / 4, 256, 0, stream>>>(KVp, gk, 32768, 2048);
  attn_kernel<<<256, 256, 0, stream>>>(Qm, KVp, mask, Om);
  gemm128<0><<<dim3(8, 8), 256, 0, stream>>>(Om, WoutT, out, 1024, 1024, 1024, 1024, 1024, 1024);
}

// Round 2
// 569.200 us; speedup vs baseline: 1.1893x; 1.1893x over previous
//
#include <hip/hip_runtime.h>
#include <cfloat>
#include <cstdint>

// ---------------------------------------------------------------------------
// AttentionPool: LN(q) @ Wq ; kv @ Wkv -> K,V ; per-head RMSNorm(Q,K) fused
// into GEMM epilogues; masked flash attention; out @ Wout.
// B=8, Nq=128, Nkv=4096, H=16, D=64. fp16 MFMA (16x16x32), fp32 accumulate.
// KV GEMM: 256x256 tile, BK=32, 4-ring LDS (128 KiB), counted vmcnt(4),
// 1 barrier per K-tile, XOR bank swizzle, XCD-aware block swizzle, setprio.
// ---------------------------------------------------------------------------

typedef _Float16 f16;
typedef _Float16 f16x8 __attribute__((ext_vector_type(8)));
typedef _Float16 f16x4 __attribute__((ext_vector_type(4)));
typedef float    f32x4 __attribute__((ext_vector_type(4)));

#define DEV __device__ __forceinline__

DEV f32x4 mfma16(f16x8 a, f16x8 b, f32x4 c) {
  return __builtin_amdgcn_mfma_f32_16x16x32_f16(a, b, c, 0, 0, 0);
}

DEV void gl_lds16(const void* g, void* l) {
  __builtin_amdgcn_global_load_lds(
      (const __attribute__((address_space(1))) uint32_t*)g,
      (__attribute__((address_space(3))) uint32_t*)l, 16, 0, 0);
}

// --------------------------- elementwise kernels ---------------------------

__global__ __launch_bounds__(256) void cast_f16_kernel(
    const float* __restrict__ src, f16* __restrict__ dst, int n4) {
  int stride = gridDim.x * 256;
  for (int i = blockIdx.x * 256 + threadIdx.x; i < n4; i += stride) {
    float4 v = ((const float4*)src)[i];
    f16x4 o = { (f16)v.x, (f16)v.y, (f16)v.z, (f16)v.w };
    ((f16x4*)dst)[i] = o;
  }
}

// transpose fp32 [R][ldsrc] -> f16 [C][lddst]; R,C multiples of 32
__global__ __launch_bounds__(256) void transpose_cast_kernel(
    const float* __restrict__ src, f16* __restrict__ dst, int ldsrc, int lddst) {
  __shared__ float tile[32][33];
  int c0 = blockIdx.x * 32, r0 = blockIdx.y * 32;
  int tx = threadIdx.x & 31, ty = threadIdx.x >> 5;  // 32 x 8
  #pragma unroll
  for (int i = 0; i < 4; ++i)
    tile[ty + i * 8][tx] = src[(long)(r0 + ty + i * 8) * ldsrc + c0 + tx];
  __syncthreads();
  #pragma unroll
  for (int i = 0; i < 4; ++i)
    dst[(long)(c0 + ty + i * 8) * lddst + r0 + tx] = (f16)tile[tx][ty + i * 8];
}

// LayerNorm over 1024, one block per row
__global__ __launch_bounds__(256) void ln_kernel(
    const float* __restrict__ q, const float* __restrict__ w, f16* __restrict__ qn) {
  int row = blockIdx.x, tid = threadIdx.x;
  float4 v = ((const float4*)(q + (long)row * 1024))[tid];
  float s1 = v.x + v.y + v.z + v.w;
  float s2 = v.x * v.x + v.y * v.y + v.z * v.z + v.w * v.w;
  #pragma unroll
  for (int off = 1; off < 64; off <<= 1) {
    s1 += __shfl_xor(s1, off);
    s2 += __shfl_xor(s2, off);
  }
  __shared__ float r1[4], r2[4];
  int wid = tid >> 6;
  if ((tid & 63) == 0) { r1[wid] = s1; r2[wid] = s2; }
  __syncthreads();
  s1 = r1[0] + r1[1] + r1[2] + r1[3];
  s2 = r2[0] + r2[1] + r2[2] + r2[3];
  float mu = s1 * (1.0f / 1024.0f);
  float var = s2 * (1.0f / 1024.0f) - mu * mu;
  float rstd = rsqrtf(var + 1e-5f);
  float4 wv = ((const float4*)w)[tid];
  f16x4 o = { (f16)((v.x - mu) * rstd * wv.x), (f16)((v.y - mu) * rstd * wv.y),
              (f16)((v.z - mu) * rstd * wv.z), (f16)((v.w - mu) * rstd * wv.w) };
  ((f16x4*)(qn + (long)row * 1024))[tid] = o;
}

// ------------------------ GEMM 128x128 (small mats) ------------------------
// C[M][N] = A[M][K] @ BT[N][K]^T. Optional fused per-64-col RMSNorm epilogue.
template <int OUT_F16, int NORM>
__global__ __launch_bounds__(256) void gemm128(
    const f16* __restrict__ A, const f16* __restrict__ BT, void* __restrict__ C,
    const float* __restrict__ gamma,
    int M, int N, int K, int lda, int ldb, int ldc) {
  __shared__ f16 tA[128 * 32];
  __shared__ f16 tB[128 * 32];
  const int tid = threadIdx.x, lane = tid & 63, wid = tid >> 6;
  const int wr = wid >> 1, wc = wid & 1;
  const int c = lane & 15, g = lane >> 4;
  const int m0 = blockIdx.y * 128, n0 = blockIdx.x * 128;
  f32x4 acc[4][4] = {};
  for (int k0 = 0; k0 < K; k0 += 32) {
    __syncthreads();
    #pragma unroll
    for (int ii = 0; ii < 2; ++ii) {
      int i = tid + ii * 256;
      gl_lds16(A + (long)(m0 + (i >> 2)) * lda + k0 + (i & 3) * 8, tA + i * 8);
    }
    #pragma unroll
    for (int ii = 0; ii < 2; ++ii) {
      int i = tid + ii * 256;
      gl_lds16(BT + (long)(n0 + (i >> 2)) * ldb + k0 + (i & 3) * 8, tB + i * 8);
    }
    __syncthreads();
    f16x8 af[4], bfr[4];
    #pragma unroll
    for (int mi = 0; mi < 4; ++mi)
      af[mi] = *(const f16x8*)&tA[(wr * 64 + mi * 16 + c) * 32 + g * 8];
    #pragma unroll
    for (int ni = 0; ni < 4; ++ni)
      bfr[ni] = *(const f16x8*)&tB[(wc * 64 + ni * 16 + c) * 32 + g * 8];
    #pragma unroll
    for (int mi = 0; mi < 4; ++mi)
      #pragma unroll
      for (int ni = 0; ni < 4; ++ni)
        acc[mi][ni] = mfma16(af[mi], bfr[ni], acc[mi][ni]);
  }
  float gam[4];
  if (NORM) {
    #pragma unroll
    for (int ni = 0; ni < 4; ++ni) gam[ni] = gamma[n0 + wc * 64 + ni * 16 + c];
    #pragma unroll
    for (int mi = 0; mi < 4; ++mi)
      #pragma unroll
      for (int j = 0; j < 4; ++j) {
        float s = 0.f;
        #pragma unroll
        for (int ni = 0; ni < 4; ++ni) { float x = acc[mi][ni][j]; s += x * x; }
        s += __shfl_xor(s, 1); s += __shfl_xor(s, 2);
        s += __shfl_xor(s, 4); s += __shfl_xor(s, 8);
        float sc = 8.0f / fmaxf(sqrtf(s), 1e-12f);
        #pragma unroll
        for (int ni = 0; ni < 4; ++ni) acc[mi][ni][j] *= sc * gam[ni];
      }
  }
  #pragma unroll
  for (int mi = 0; mi < 4; ++mi)
    #pragma unroll
    for (int ni = 0; ni < 4; ++ni)
      #pragma unroll
      for (int j = 0; j < 4; ++j) {
        int row = m0 + wr * 64 + mi * 16 + g * 4 + j;
        int col = n0 + wc * 64 + ni * 16 + c;
        if (OUT_F16) ((f16*)C)[(long)row * ldc + col] = (f16)acc[mi][ni][j];
        else        ((float*)C)[(long)row * ldc + col] = acc[mi][ni][j];
      }
}

// -------------------- GEMM 256x256, BK=32, 4-ring (KV) ---------------------
// Race-free counted-vmcnt pipeline:
//  - ring r = kt & 3; during kt we stage kt+2 (ring disjoint from any ring
//    readable within the <=1-tile barrier skew), so no LDS write/read race.
//  - boundary per K-tile: s_waitcnt vmcnt(4) (kt+1's 4 loads stay in flight;
//    never drained to 0 in the main loop) + raw s_barrier.
//  - LDS XOR swizzle slot^=(row&3) applied on the pre-swizzled global source
//    (linear gl_lds dest) and on ds_read addresses: conflict-free b128 reads.
//  - epilogue optionally fuses per-head (64-col) RMSNorm for cols < normLim.
__global__ __launch_bounds__(512, 2) void gemm256(
    const f16* __restrict__ A, const f16* __restrict__ BT, f16* __restrict__ C,
    const float* __restrict__ gamma, int normLim,
    int K, int lda, int ldb, int ldc, int mtiles, int ntiles) {
  __shared__ f16 lds[4 * 16384];  // 4 rings x (A 8K f16 + B 8K f16) = 128 KiB
  const int tid = threadIdx.x, lane = tid & 63, wid = tid >> 6;
  const int wr = wid >> 2, wc = wid & 3;  // 2 x 4 waves, per-wave C 128x64
  const int c = lane & 15, g = lane >> 4;
  // bijective XCD swizzle (nwg % 8 == 0): each XCD gets a contiguous m-chunk
  const int nwg = mtiles * ntiles, cpx = nwg >> 3;
  const int bid = blockIdx.x;
  const int wg = (bid & 7) * cpx + (bid >> 3);
  const int n0 = (wg % ntiles) * 256;
  const long m0 = (long)(wg / ntiles) * 256;

  const int nkt = K >> 5;
  const int r1 = tid >> 2, r2 = 128 + (tid >> 2), sl = tid & 3;
  const int sw1 = (sl ^ (r1 & 3)) << 3, sw2 = (sl ^ (r2 & 3)) << 3;

  f32x4 acc[8][4] = {};

  #define STAGE_A(kt_) do { int kt__ = (kt_);                                   \
    f16* dst = lds + ((kt__) & 3) * 16384; int k0 = (kt__) << 5;                \
    gl_lds16(A + (m0 + r1) * lda + k0 + sw1, dst + (long)tid * 8);              \
    gl_lds16(A + (m0 + r2) * lda + k0 + sw2, dst + (long)(tid + 512) * 8);      \
  } while (0)
  #define STAGE_B(kt_) do { int kt__ = (kt_);                                   \
    f16* dst = lds + ((kt__) & 3) * 16384 + 8192; int k0 = (kt__) << 5;         \
    gl_lds16(BT + (long)(n0 + r1) * ldb + k0 + sw1, dst + (long)tid * 8);       \
    gl_lds16(BT + (long)(n0 + r2) * ldb + k0 + sw2, dst + (long)(tid + 512) * 8);\
  } while (0)

  // prologue: kt0 + kt1 staged; wait kt0 (4 of kt1's stay in flight)
  STAGE_A(0); STAGE_B(0); STAGE_A(1); STAGE_B(1);
  asm volatile("s_waitcnt vmcnt(4)" ::: "memory");
  __builtin_amdgcn_s_barrier();

  for (int kt = 0; kt < nkt; ++kt) {
    const f16* la = lds + (kt & 3) * 16384;
    const f16* lb = la + 8192;
    const bool pre = (kt + 2) < nkt;
    // ---- phase 0: stage A(kt+2) | read B + A-low | MFMA mi 0..3 ----
    if (pre) STAGE_A(kt + 2);
    f16x8 bfr[4], afr[4];
    #pragma unroll
    for (int ni = 0; ni < 4; ++ni) {
      int r = wc * 64 + ni * 16 + c;
      bfr[ni] = *(const f16x8*)&lb[r * 32 + ((g ^ (r & 3)) << 3)];
    }
    #pragma unroll
    for (int q = 0; q < 4; ++q) {
      int r = wr * 128 + q * 16 + c;
      afr[q] = *(const f16x8*)&la[r * 32 + ((g ^ (r & 3)) << 3)];
    }
    __builtin_amdgcn_s_setprio(1);
    #pragma unroll
    for (int q = 0; q < 4; ++q)
      #pragma unroll
      for (int ni = 0; ni < 4; ++ni)
        acc[q][ni] = mfma16(afr[q], bfr[ni], acc[q][ni]);
    __builtin_amdgcn_s_setprio(0);
    // ---- phase 1: stage B(kt+2) | read A-high | MFMA mi 4..7 ----
    if (pre) STAGE_B(kt + 2);
    #pragma unroll
    for (int q = 0; q < 4; ++q) {
      int r = wr * 128 + 64 + q * 16 + c;
      afr[q] = *(const f16x8*)&la[r * 32 + ((g ^ (r & 3)) << 3)];
    }
    __builtin_amdgcn_s_setprio(1);
    #pragma unroll
    for (int q = 0; q < 4; ++q)
      #pragma unroll
      for (int ni = 0; ni < 4; ++ni)
        acc[4 + q][ni] = mfma16(afr[q], bfr[ni], acc[4 + q][ni]);
    __builtin_amdgcn_s_setprio(0);
    // ---- K-tile boundary: counted wait (kt+1 resident, kt+2 in flight) ----
    if (pre) { asm volatile("s_waitcnt vmcnt(4)" ::: "memory"); }
    else     { asm volatile("s_waitcnt vmcnt(0)" ::: "memory"); }
    __builtin_amdgcn_s_barrier();
  }
  #undef STAGE_A
  #undef STAGE_B

  // epilogue: optional fused per-head RMSNorm (wave spans exactly one head)
  const int colbase = n0 + wc * 64;
  if (colbase < normLim) {
    float gam[4];
    #pragma unroll
    for (int ni = 0; ni < 4; ++ni) gam[ni] = gamma[colbase + ni * 16 + c];
    #pragma unroll
    for (int mi = 0; mi < 8; ++mi)
      #pragma unroll
      for (int j = 0; j < 4; ++j) {
        float s = 0.f;
        #pragma unroll
        for (int ni = 0; ni < 4; ++ni) { float x = acc[mi][ni][j]; s += x * x; }
        s += __shfl_xor(s, 1); s += __shfl_xor(s, 2);
        s += __shfl_xor(s, 4); s += __shfl_xor(s, 8);
        float sc = 8.0f / fmaxf(sqrtf(s), 1e-12f);
        #pragma unroll
        for (int ni = 0; ni < 4; ++ni) acc[mi][ni][j] *= sc * gam[ni];
      }
  }
  #pragma unroll
  for (int mi = 0; mi < 8; ++mi)
    #pragma unroll
    for (int j = 0; j < 4; ++j) {
      long row = m0 + wr * 128 + mi * 16 + g * 4 + j;
      #pragma unroll
      for (int ni = 0; ni < 4; ++ni)
        C[row * ldc + colbase + ni * 16 + c] = (f16)acc[mi][ni][j];
    }
}

// ---------------------------- flash attention ------------------------------
__global__ __launch_bounds__(256) void attn_kernel(
    const f16* __restrict__ Q, const f16* __restrict__ KV,
    const int* __restrict__ mask, f16* __restrict__ O) {
  __shared__ f16 Kt[64 * 64];       // XOR-swizzled [kv][64]
  __shared__ f16 Vt[64 * 72];       // transposed [d][kv], stride 72
  __shared__ f16 Pl[4 * 16 * 72];   // per-wave P [16 q][64 kv], stride 72
  const int blk = blockIdx.x;
  const int half = blk & 1, h = (blk >> 1) & 15, b = blk >> 5;
  const int tid = threadIdx.x, lane = tid & 63, wid = tid >> 6;
  const int c = lane & 15, g = lane >> 4;

  const int qrow = b * 128 + half * 64 + wid * 16 + c;
  f16x8 qa[2];
  #pragma unroll
  for (int kk = 0; kk < 2; ++kk)
    qa[kk] = *(const f16x8*)&Q[(long)qrow * 1024 + h * 64 + kk * 32 + g * 8];

  float m_[4], l_[4];
  f32x4 o_[4];
  #pragma unroll
  for (int j = 0; j < 4; ++j) { m_[j] = -FLT_MAX; l_[j] = 0.f; }
  #pragma unroll
  for (int ni = 0; ni < 4; ++ni) o_[ni] = (f32x4){0.f, 0.f, 0.f, 0.f};

  const long kvbase = (long)b * 4096 * 2048;
  f16* Pw = Pl + wid * 16 * 72;

  for (int kt = 0; kt < 64; ++kt) {
    __syncthreads();
    #pragma unroll
    for (int ii = 0; ii < 2; ++ii) {
      int i = tid + ii * 256;
      int r = i >> 3, s = i & 7;
      gl_lds16(KV + kvbase + (long)(kt * 64 + r) * 2048 + h * 64 + ((s ^ (r & 7)) * 8),
               Kt + i * 8);
    }
    #pragma unroll
    for (int ii = 0; ii < 2; ++ii) {
      int i = tid + ii * 256;
      int kv = i & 63, d0 = (i >> 6) * 8;
      f16x8 v = *(const f16x8*)&KV[kvbase + (long)(kt * 64 + kv) * 2048 + 1024 + h * 64 + d0];
      #pragma unroll
      for (int j = 0; j < 8; ++j) Vt[(d0 + j) * 72 + kv] = v[j];
    }
    __syncthreads();

    f32x4 s4[4];
    #pragma unroll
    for (int ni = 0; ni < 4; ++ni) {
      s4[ni] = (f32x4){0.f, 0.f, 0.f, 0.f};
      int kvr = ni * 16 + c;
      #pragma unroll
      for (int kk = 0; kk < 2; ++kk) {
        int slot = (kk * 4 + g) ^ (kvr & 7);
        f16x8 kb = *(const f16x8*)&Kt[kvr * 64 + slot * 8];
        s4[ni] = mfma16(qa[kk], kb, s4[ni]);
      }
    }

    int msk[4];
    #pragma unroll
    for (int ni = 0; ni < 4; ++ni) {
      msk[ni] = mask[b * 4096 + kt * 64 + ni * 16 + c];
      if (!msk[ni]) s4[ni] = (f32x4){-FLT_MAX, -FLT_MAX, -FLT_MAX, -FLT_MAX};
    }

    float mnew[4], alpha[4], psum[4];
    #pragma unroll
    for (int j = 0; j < 4; ++j) {
      float v = fmaxf(fmaxf(s4[0][j], s4[1][j]), fmaxf(s4[2][j], s4[3][j]));
      v = fmaxf(v, __shfl_xor(v, 1));
      v = fmaxf(v, __shfl_xor(v, 2));
      v = fmaxf(v, __shfl_xor(v, 4));
      v = fmaxf(v, __shfl_xor(v, 8));
      mnew[j] = fmaxf(m_[j], v);
      alpha[j] = __expf(m_[j] - mnew[j]);
      m_[j] = mnew[j];
      psum[j] = 0.f;
    }
    f16 pb[4][4];
    #pragma unroll
    for (int ni = 0; ni < 4; ++ni)
      #pragma unroll
      for (int j = 0; j < 4; ++j) {
        float p = msk[ni] ? __expf(s4[ni][j] - mnew[j]) : 0.0f;
        psum[j] += p;
        pb[ni][j] = (f16)p;
      }
    #pragma unroll
    for (int j = 0; j < 4; ++j) {
      float ps = psum[j];
      ps += __shfl_xor(ps, 1);
      ps += __shfl_xor(ps, 2);
      ps += __shfl_xor(ps, 4);
      ps += __shfl_xor(ps, 8);
      l_[j] = alpha[j] * l_[j] + ps;
    }
    #pragma unroll
    for (int ni = 0; ni < 4; ++ni)
      #pragma unroll
      for (int j = 0; j < 4; ++j)
        Pw[(g * 4 + j) * 72 + ni * 16 + c] = pb[ni][j];
    #pragma unroll
    for (int ni = 0; ni < 4; ++ni)
      #pragma unroll
      for (int j = 0; j < 4; ++j)
        o_[ni][j] *= alpha[j];
    f16x8 pa[2];
    #pragma unroll
    for (int kk = 0; kk < 2; ++kk)
      pa[kk] = *(const f16x8*)&Pw[c * 72 + kk * 32 + g * 8];
    #pragma unroll
    for (int ni = 0; ni < 4; ++ni)
      #pragma unroll
      for (int kk = 0; kk < 2; ++kk) {
        f16x8 vb = *(const f16x8*)&Vt[(ni * 16 + c) * 72 + kk * 32 + g * 8];
        o_[ni] = mfma16(pa[kk], vb, o_[ni]);
      }
  }

  #pragma unroll
  for (int j = 0; j < 4; ++j) {
    float inv = 1.0f / fmaxf(l_[j], 1e-30f);
    int row = b * 128 + half * 64 + wid * 16 + g * 4 + j;
    #pragma unroll
    for (int ni = 0; ni < 4; ++ni) {
      int col = h * 64 + ni * 16 + c;
      O[(long)row * 1024 + col] = (f16)(o_[ni][j] * inv);
    }
  }
}

// ------------------------------- launcher ----------------------------------

extern "C" void kernel_launch(void* const* d_in, const int* in_sizes, int n_in,
                              void* d_out, int out_size, void* d_ws, size_t ws_size,
                              hipStream_t stream) {
  const float* q    = (const float*)d_in[0];
  const float* kv   = (const float*)d_in[1];
  const int*   mask = (const int*)d_in[2];
  const float* ln_w = (const float*)d_in[3];
  const float* gq   = (const float*)d_in[4];
  const float* gk   = (const float*)d_in[5];
  const float* Wq   = (const float*)d_in[6];
  const float* Wkv  = (const float*)d_in[7];
  const float* Wout = (const float*)d_in[8];
  float* out = (float*)d_out;
  char* ws = (char*)d_ws;
  const size_t MB = (size_t)1 << 20;
  f16* qn    = (f16*)(ws + 0 * MB);    // 2 MB   [1024][1024]
  f16* Qm    = (f16*)(ws + 2 * MB);    // 2 MB   [1024][1024]
  f16* Om    = (f16*)(ws + 4 * MB);    // 2 MB   [1024][1024]
  f16* WqT   = (f16*)(ws + 6 * MB);    // 2 MB   [1024][1024]
  f16* WkvT  = (f16*)(ws + 8 * MB);    // 4 MB   [2048][1024]
  f16* WoutT = (f16*)(ws + 12 * MB);   // 2 MB   [1024][1024]
  f16* kv16  = (f16*)(ws + 14 * MB);   // 64 MB  [32768][1024]
  f16* KVp   = (f16*)(ws + 78 * MB);   // 128 MB [32768][2048]

  cast_f16_kernel<<<2048, 256, 0, stream>>>(kv, kv16, 8 * 4096 * 1024 / 4);
  transpose_cast_kernel<<<dim3(32, 32), 256, 0, stream>>>(Wq, WqT, 1024, 1024);
  transpose_cast_kernel<<<dim3(64, 32), 256, 0, stream>>>(Wkv, WkvT, 2048, 1024);
  transpose_cast_kernel<<<dim3(32, 32), 256, 0, stream>>>(Wout, WoutT, 1024, 1024);
  ln_kernel<<<1024, 256, 0, stream>>>(q, ln_w, qn);
  // Q projection + fused RMSNorm(gamma_q)
  gemm128<1, 1><<<dim3(8, 8), 256, 0, stream>>>(qn, WqT, Qm, gq,
                                                1024, 1024, 1024, 1024, 1024, 1024);
  // KV projection + fused RMSNorm(gamma_k) on K half (cols < 1024)
  gemm256<<<1024, 512, 0, stream>>>(kv16, WkvT, KVp, gk, 1024,
                                    1024, 1024, 1024, 2048, 128, 8);
  attn_kernel<<<256, 256, 0, stream>>>(Qm, KVp, mask, Om);
  gemm128<0, 0><<<dim3(8, 8), 256, 0, stream>>>(Om, WoutT, out, nullptr,
                                                1024, 1024, 1024, 1024, 1024, 1024);
}

// Round 3
// 515.465 us; speedup vs baseline: 1.3133x; 1.1042x over previous
//
#include <hip/hip_runtime.h>
#include <cfloat>
#include <cstdint>

// ---------------------------------------------------------------------------
// AttentionPool: LN(q) @ Wq ; kv @ Wkv -> K,V ; per-head RMSNorm(Q,K) fused
// into GEMM epilogues; masked flash attention (split-KV, 4 chunks + merge);
// out @ Wout.  B=8, Nq=128, Nkv=4096, H=16, D=64. fp16 MFMA, fp32 accum.
// gemm256: 256x256 tile, BK=32, 4-ring LDS, counted vmcnt(4), 1 barrier/tile,
// XOR swizzle slot^=(r>>1)&3 (bank-group = (4r+slot)%8 -> conflict-free).
// ---------------------------------------------------------------------------

typedef _Float16 f16;
typedef _Float16 f16x8 __attribute__((ext_vector_type(8)));
typedef _Float16 f16x4 __attribute__((ext_vector_type(4)));
typedef float    f32x4 __attribute__((ext_vector_type(4)));

#define DEV __device__ __forceinline__

DEV f32x4 mfma16(f16x8 a, f16x8 b, f32x4 c) {
  return __builtin_amdgcn_mfma_f32_16x16x32_f16(a, b, c, 0, 0, 0);
}

DEV void gl_lds16(const void* g, void* l) {
  __builtin_amdgcn_global_load_lds(
      (const __attribute__((address_space(1))) uint32_t*)g,
      (__attribute__((address_space(3))) uint32_t*)l, 16, 0, 0);
}

// --------------------------- elementwise kernels ---------------------------

__global__ __launch_bounds__(256) void cast_f16_kernel(
    const float* __restrict__ src, f16* __restrict__ dst, int n4) {
  int stride = gridDim.x * 256;
  for (int i = blockIdx.x * 256 + threadIdx.x; i < n4; i += stride) {
    float4 v = ((const float4*)src)[i];
    f16x4 o = { (f16)v.x, (f16)v.y, (f16)v.z, (f16)v.w };
    ((f16x4*)dst)[i] = o;
  }
}

// transpose fp32 [R][ldsrc] -> f16 [C][lddst]; R,C multiples of 32
__global__ __launch_bounds__(256) void transpose_cast_kernel(
    const float* __restrict__ src, f16* __restrict__ dst, int ldsrc, int lddst) {
  __shared__ float tile[32][33];
  int c0 = blockIdx.x * 32, r0 = blockIdx.y * 32;
  int tx = threadIdx.x & 31, ty = threadIdx.x >> 5;  // 32 x 8
  #pragma unroll
  for (int i = 0; i < 4; ++i)
    tile[ty + i * 8][tx] = src[(long)(r0 + ty + i * 8) * ldsrc + c0 + tx];
  __syncthreads();
  #pragma unroll
  for (int i = 0; i < 4; ++i)
    dst[(long)(c0 + ty + i * 8) * lddst + r0 + tx] = (f16)tile[tx][ty + i * 8];
}

// LayerNorm over 1024, one block per row
__global__ __launch_bounds__(256) void ln_kernel(
    const float* __restrict__ q, const float* __restrict__ w, f16* __restrict__ qn) {
  int row = blockIdx.x, tid = threadIdx.x;
  float4 v = ((const float4*)(q + (long)row * 1024))[tid];
  float s1 = v.x + v.y + v.z + v.w;
  float s2 = v.x * v.x + v.y * v.y + v.z * v.z + v.w * v.w;
  #pragma unroll
  for (int off = 1; off < 64; off <<= 1) {
    s1 += __shfl_xor(s1, off);
    s2 += __shfl_xor(s2, off);
  }
  __shared__ float r1[4], r2[4];
  int wid = tid >> 6;
  if ((tid & 63) == 0) { r1[wid] = s1; r2[wid] = s2; }
  __syncthreads();
  s1 = r1[0] + r1[1] + r1[2] + r1[3];
  s2 = r2[0] + r2[1] + r2[2] + r2[3];
  float mu = s1 * (1.0f / 1024.0f);
  float var = s2 * (1.0f / 1024.0f) - mu * mu;
  float rstd = rsqrtf(var + 1e-5f);
  float4 wv = ((const float4*)w)[tid];
  f16x4 o = { (f16)((v.x - mu) * rstd * wv.x), (f16)((v.y - mu) * rstd * wv.y),
              (f16)((v.z - mu) * rstd * wv.z), (f16)((v.w - mu) * rstd * wv.w) };
  ((f16x4*)(qn + (long)row * 1024))[tid] = o;
}

// ------------------------ GEMM 128x128 (small mats) ------------------------
template <int OUT_F16, int NORM>
__global__ __launch_bounds__(256) void gemm128(
    const f16* __restrict__ A, const f16* __restrict__ BT, void* __restrict__ C,
    const float* __restrict__ gamma,
    int M, int N, int K, int lda, int ldb, int ldc) {
  __shared__ f16 tA[128 * 32];
  __shared__ f16 tB[128 * 32];
  const int tid = threadIdx.x, lane = tid & 63, wid = tid >> 6;
  const int wr = wid >> 1, wc = wid & 1;
  const int c = lane & 15, g = lane >> 4;
  const int m0 = blockIdx.y * 128, n0 = blockIdx.x * 128;
  f32x4 acc[4][4] = {};
  for (int k0 = 0; k0 < K; k0 += 32) {
    __syncthreads();
    #pragma unroll
    for (int ii = 0; ii < 2; ++ii) {
      int i = tid + ii * 256;
      gl_lds16(A + (long)(m0 + (i >> 2)) * lda + k0 + (i & 3) * 8, tA + i * 8);
    }
    #pragma unroll
    for (int ii = 0; ii < 2; ++ii) {
      int i = tid + ii * 256;
      gl_lds16(BT + (long)(n0 + (i >> 2)) * ldb + k0 + (i & 3) * 8, tB + i * 8);
    }
    __syncthreads();
    f16x8 af[4], bfr[4];
    #pragma unroll
    for (int mi = 0; mi < 4; ++mi)
      af[mi] = *(const f16x8*)&tA[(wr * 64 + mi * 16 + c) * 32 + g * 8];
    #pragma unroll
    for (int ni = 0; ni < 4; ++ni)
      bfr[ni] = *(const f16x8*)&tB[(wc * 64 + ni * 16 + c) * 32 + g * 8];
    #pragma unroll
    for (int mi = 0; mi < 4; ++mi)
      #pragma unroll
      for (int ni = 0; ni < 4; ++ni)
        acc[mi][ni] = mfma16(af[mi], bfr[ni], acc[mi][ni]);
  }
  float gam[4];
  if (NORM) {
    #pragma unroll
    for (int ni = 0; ni < 4; ++ni) gam[ni] = gamma[n0 + wc * 64 + ni * 16 + c];
    #pragma unroll
    for (int mi = 0; mi < 4; ++mi)
      #pragma unroll
      for (int j = 0; j < 4; ++j) {
        float s = 0.f;
        #pragma unroll
        for (int ni = 0; ni < 4; ++ni) { float x = acc[mi][ni][j]; s += x * x; }
        s += __shfl_xor(s, 1); s += __shfl_xor(s, 2);
        s += __shfl_xor(s, 4); s += __shfl_xor(s, 8);
        float sc = 8.0f / fmaxf(sqrtf(s), 1e-12f);
        #pragma unroll
        for (int ni = 0; ni < 4; ++ni) acc[mi][ni][j] *= sc * gam[ni];
      }
  }
  #pragma unroll
  for (int mi = 0; mi < 4; ++mi)
    #pragma unroll
    for (int ni = 0; ni < 4; ++ni)
      #pragma unroll
      for (int j = 0; j < 4; ++j) {
        int row = m0 + wr * 64 + mi * 16 + g * 4 + j;
        int col = n0 + wc * 64 + ni * 16 + c;
        if (OUT_F16) ((f16*)C)[(long)row * ldc + col] = (f16)acc[mi][ni][j];
        else        ((float*)C)[(long)row * ldc + col] = acc[mi][ni][j];
      }
}

// -------------------- GEMM 256x256, BK=32, 4-ring (KV) ---------------------
// Counted-vmcnt ring pipeline; XOR swizzle slot^=(r>>1)&3 on pre-swizzled
// global source (linear gl_lds dest) and on ds_read addresses.
// bank-group(16B) = (4*r + slot) % 8 -> distinct for 8 consecutive lanes.
__global__ __launch_bounds__(512, 2) void gemm256(
    const f16* __restrict__ A, const f16* __restrict__ BT, f16* __restrict__ C,
    const float* __restrict__ gamma, int normLim,
    int K, int lda, int ldb, int ldc, int mtiles, int ntiles) {
  __shared__ f16 lds[4 * 16384];  // 4 rings x (A 8K f16 + B 8K f16) = 128 KiB
  const int tid = threadIdx.x, lane = tid & 63, wid = tid >> 6;
  const int wr = wid >> 2, wc = wid & 3;  // 2 x 4 waves, per-wave C 128x64
  const int c = lane & 15, g = lane >> 4;
  const int nwg = mtiles * ntiles, cpx = nwg >> 3;
  const int bid = blockIdx.x;
  const int wg = (bid & 7) * cpx + (bid >> 3);
  const int n0 = (wg % ntiles) * 256;
  const long m0 = (long)(wg / ntiles) * 256;

  const int nkt = K >> 5;
  const int r1 = tid >> 2, r2 = 128 + (tid >> 2), sl = tid & 3;
  const int sw1 = (sl ^ ((r1 >> 1) & 3)) << 3, sw2 = (sl ^ ((r2 >> 1) & 3)) << 3;

  f32x4 acc[8][4] = {};

  #define STAGE_A(kt_) do { int kt__ = (kt_);                                   \
    f16* dst = lds + ((kt__) & 3) * 16384; int k0 = (kt__) << 5;                \
    gl_lds16(A + (m0 + r1) * lda + k0 + sw1, dst + (long)tid * 8);              \
    gl_lds16(A + (m0 + r2) * lda + k0 + sw2, dst + (long)(tid + 512) * 8);      \
  } while (0)
  #define STAGE_B(kt_) do { int kt__ = (kt_);                                   \
    f16* dst = lds + ((kt__) & 3) * 16384 + 8192; int k0 = (kt__) << 5;         \
    gl_lds16(BT + (long)(n0 + r1) * ldb + k0 + sw1, dst + (long)tid * 8);       \
    gl_lds16(BT + (long)(n0 + r2) * ldb + k0 + sw2, dst + (long)(tid + 512) * 8);\
  } while (0)

  STAGE_A(0); STAGE_B(0); STAGE_A(1); STAGE_B(1);
  asm volatile("s_waitcnt vmcnt(4)" ::: "memory");
  __builtin_amdgcn_s_barrier();

  for (int kt = 0; kt < nkt; ++kt) {
    const f16* la = lds + (kt & 3) * 16384;
    const f16* lb = la + 8192;
    const bool pre = (kt + 2) < nkt;
    if (pre) STAGE_A(kt + 2);
    f16x8 bfr[4], afr[4];
    #pragma unroll
    for (int ni = 0; ni < 4; ++ni) {
      int r = wc * 64 + ni * 16 + c;
      bfr[ni] = *(const f16x8*)&lb[r * 32 + ((g ^ ((r >> 1) & 3)) << 3)];
    }
    #pragma unroll
    for (int q = 0; q < 4; ++q) {
      int r = wr * 128 + q * 16 + c;
      afr[q] = *(const f16x8*)&la[r * 32 + ((g ^ ((r >> 1) & 3)) << 3)];
    }
    __builtin_amdgcn_s_setprio(1);
    #pragma unroll
    for (int q = 0; q < 4; ++q)
      #pragma unroll
      for (int ni = 0; ni < 4; ++ni)
        acc[q][ni] = mfma16(afr[q], bfr[ni], acc[q][ni]);
    __builtin_amdgcn_s_setprio(0);
    if (pre) STAGE_B(kt + 2);
    #pragma unroll
    for (int q = 0; q < 4; ++q) {
      int r = wr * 128 + 64 + q * 16 + c;
      afr[q] = *(const f16x8*)&la[r * 32 + ((g ^ ((r >> 1) & 3)) << 3)];
    }
    __builtin_amdgcn_s_setprio(1);
    #pragma unroll
    for (int q = 0; q < 4; ++q)
      #pragma unroll
      for (int ni = 0; ni < 4; ++ni)
        acc[4 + q][ni] = mfma16(afr[q], bfr[ni], acc[4 + q][ni]);
    __builtin_amdgcn_s_setprio(0);
    if (pre) { asm volatile("s_waitcnt vmcnt(4)" ::: "memory"); }
    else     { asm volatile("s_waitcnt vmcnt(0)" ::: "memory"); }
    __builtin_amdgcn_s_barrier();
  }
  #undef STAGE_A
  #undef STAGE_B

  const int colbase = n0 + wc * 64;
  if (colbase < normLim) {
    float gam[4];
    #pragma unroll
    for (int ni = 0; ni < 4; ++ni) gam[ni] = gamma[colbase + ni * 16 + c];
    #pragma unroll
    for (int mi = 0; mi < 8; ++mi)
      #pragma unroll
      for (int j = 0; j < 4; ++j) {
        float s = 0.f;
        #pragma unroll
        for (int ni = 0; ni < 4; ++ni) { float x = acc[mi][ni][j]; s += x * x; }
        s += __shfl_xor(s, 1); s += __shfl_xor(s, 2);
        s += __shfl_xor(s, 4); s += __shfl_xor(s, 8);
        float sc = 8.0f / fmaxf(sqrtf(s), 1e-12f);
        #pragma unroll
        for (int ni = 0; ni < 4; ++ni) acc[mi][ni][j] *= sc * gam[ni];
      }
  }
  #pragma unroll
  for (int mi = 0; mi < 8; ++mi)
    #pragma unroll
    for (int j = 0; j < 4; ++j) {
      long row = m0 + wr * 128 + mi * 16 + g * 4 + j;
      #pragma unroll
      for (int ni = 0; ni < 4; ++ni)
        C[row * ldc + colbase + ni * 16 + c] = (f16)acc[mi][ni][j];
    }
}

// ------------------- flash attention, split-KV (4 chunks) ------------------
// grid 1024 = (chunk, b, h, half). Each block: 16 KV-tiles of 64 rows.
// Writes unnormalized partial O (f32) + per-row (m, l) to workspace.
__global__ __launch_bounds__(256) void attn_kernel(
    const f16* __restrict__ Q, const f16* __restrict__ KV,
    const int* __restrict__ mask, float* __restrict__ Opart,
    float* __restrict__ ml) {
  __shared__ f16 Kt[64 * 64];       // XOR-swizzled [kv][64]
  __shared__ f16 Vt[64 * 72];       // transposed [d][kv], stride 72
  __shared__ f16 Pl[4 * 16 * 72];   // per-wave P [16 q][64 kv], stride 72
  const int blk = blockIdx.x;
  const int chunk = blk >> 8, sub = blk & 255;
  const int half = sub & 1, h = (sub >> 1) & 15, b = sub >> 5;
  const int tid = threadIdx.x, lane = tid & 63, wid = tid >> 6;
  const int c = lane & 15, g = lane >> 4;

  const int qrow = b * 128 + half * 64 + wid * 16 + c;
  f16x8 qa[2];
  #pragma unroll
  for (int kk = 0; kk < 2; ++kk)
    qa[kk] = *(const f16x8*)&Q[(long)qrow * 1024 + h * 64 + kk * 32 + g * 8];

  float m_[4], l_[4];
  f32x4 o_[4];
  #pragma unroll
  for (int j = 0; j < 4; ++j) { m_[j] = -FLT_MAX; l_[j] = 0.f; }
  #pragma unroll
  for (int ni = 0; ni < 4; ++ni) o_[ni] = (f32x4){0.f, 0.f, 0.f, 0.f};

  const long kvbase = (long)b * 4096 * 2048;
  f16* Pw = Pl + wid * 16 * 72;

  for (int kt = chunk * 16; kt < chunk * 16 + 16; ++kt) {
    __syncthreads();
    #pragma unroll
    for (int ii = 0; ii < 2; ++ii) {
      int i = tid + ii * 256;
      int r = i >> 3, s = i & 7;
      gl_lds16(KV + kvbase + (long)(kt * 64 + r) * 2048 + h * 64 + ((s ^ (r & 7)) * 8),
               Kt + i * 8);
    }
    #pragma unroll
    for (int ii = 0; ii < 2; ++ii) {
      int i = tid + ii * 256;
      int kv = i & 63, d0 = (i >> 6) * 8;
      f16x8 v = *(const f16x8*)&KV[kvbase + (long)(kt * 64 + kv) * 2048 + 1024 + h * 64 + d0];
      #pragma unroll
      for (int j = 0; j < 8; ++j) Vt[(d0 + j) * 72 + kv] = v[j];
    }
    __syncthreads();

    f32x4 s4[4];
    #pragma unroll
    for (int ni = 0; ni < 4; ++ni) {
      s4[ni] = (f32x4){0.f, 0.f, 0.f, 0.f};
      int kvr = ni * 16 + c;
      #pragma unroll
      for (int kk = 0; kk < 2; ++kk) {
        int slot = (kk * 4 + g) ^ (kvr & 7);
        f16x8 kb = *(const f16x8*)&Kt[kvr * 64 + slot * 8];
        s4[ni] = mfma16(qa[kk], kb, s4[ni]);
      }
    }

    int msk[4];
    #pragma unroll
    for (int ni = 0; ni < 4; ++ni) {
      msk[ni] = mask[b * 4096 + kt * 64 + ni * 16 + c];
      if (!msk[ni]) s4[ni] = (f32x4){-FLT_MAX, -FLT_MAX, -FLT_MAX, -FLT_MAX};
    }

    float mnew[4], alpha[4], psum[4];
    #pragma unroll
    for (int j = 0; j < 4; ++j) {
      float v = fmaxf(fmaxf(s4[0][j], s4[1][j]), fmaxf(s4[2][j], s4[3][j]));
      v = fmaxf(v, __shfl_xor(v, 1));
      v = fmaxf(v, __shfl_xor(v, 2));
      v = fmaxf(v, __shfl_xor(v, 4));
      v = fmaxf(v, __shfl_xor(v, 8));
      mnew[j] = fmaxf(m_[j], v);
      alpha[j] = __expf(m_[j] - mnew[j]);
      m_[j] = mnew[j];
      psum[j] = 0.f;
    }
    f16 pb[4][4];
    #pragma unroll
    for (int ni = 0; ni < 4; ++ni)
      #pragma unroll
      for (int j = 0; j < 4; ++j) {
        float p = msk[ni] ? __expf(s4[ni][j] - mnew[j]) : 0.0f;
        psum[j] += p;
        pb[ni][j] = (f16)p;
      }
    #pragma unroll
    for (int j = 0; j < 4; ++j) {
      float ps = psum[j];
      ps += __shfl_xor(ps, 1);
      ps += __shfl_xor(ps, 2);
      ps += __shfl_xor(ps, 4);
      ps += __shfl_xor(ps, 8);
      l_[j] = alpha[j] * l_[j] + ps;
    }
    #pragma unroll
    for (int ni = 0; ni < 4; ++ni)
      #pragma unroll
      for (int j = 0; j < 4; ++j)
        Pw[(g * 4 + j) * 72 + ni * 16 + c] = pb[ni][j];
    #pragma unroll
    for (int ni = 0; ni < 4; ++ni)
      #pragma unroll
      for (int j = 0; j < 4; ++j)
        o_[ni][j] *= alpha[j];
    f16x8 pa[2];
    #pragma unroll
    for (int kk = 0; kk < 2; ++kk)
      pa[kk] = *(const f16x8*)&Pw[c * 72 + kk * 32 + g * 8];
    #pragma unroll
    for (int ni = 0; ni < 4; ++ni)
      #pragma unroll
      for (int kk = 0; kk < 2; ++kk) {
        f16x8 vb = *(const f16x8*)&Vt[(ni * 16 + c) * 72 + kk * 32 + g * 8];
        o_[ni] = mfma16(pa[kk], vb, o_[ni]);
      }
  }

  // epilogue: write unnormalized partial O + (m, l)
  #pragma unroll
  for (int j = 0; j < 4; ++j) {
    int row = b * 128 + half * 64 + wid * 16 + g * 4 + j;
    #pragma unroll
    for (int ni = 0; ni < 4; ++ni)
      Opart[((long)chunk * 1024 + row) * 1024 + h * 64 + ni * 16 + c] = o_[ni][j];
    if (c == 0) {
      long u = (((long)chunk * 1024 + row) * 16 + h) * 2;
      ml[u] = m_[j];
      ml[u + 1] = l_[j];
    }
  }
}

// merge 4 partials: one wave per (row, head)
__global__ __launch_bounds__(256) void attn_merge_kernel(
    const float* __restrict__ Opart, const float* __restrict__ ml,
    f16* __restrict__ Om) {
  int unit = blockIdx.x * 4 + (threadIdx.x >> 6);
  int lane = threadIdx.x & 63;
  int row = unit >> 4, h = unit & 15;
  float mc[4], lc[4], M = -FLT_MAX;
  #pragma unroll
  for (int cI = 0; cI < 4; ++cI) {
    long u = (((long)cI * 1024 + row) * 16 + h) * 2;
    mc[cI] = ml[u]; lc[cI] = ml[u + 1];
    M = fmaxf(M, mc[cI]);
  }
  float L = 0.f, o = 0.f;
  #pragma unroll
  for (int cI = 0; cI < 4; ++cI) {
    float w = __expf(mc[cI] - M);
    L += lc[cI] * w;
    o += Opart[((long)cI * 1024 + row) * 1024 + h * 64 + lane] * w;
  }
  Om[(long)row * 1024 + h * 64 + lane] = (f16)(o / fmaxf(L, 1e-30f));
}

// ------------------------------- launcher ----------------------------------

extern "C" void kernel_launch(void* const* d_in, const int* in_sizes, int n_in,
                              void* d_out, int out_size, void* d_ws, size_t ws_size,
                              hipStream_t stream) {
  const float* q    = (const float*)d_in[0];
  const float* kv   = (const float*)d_in[1];
  const int*   mask = (const int*)d_in[2];
  const float* ln_w = (const float*)d_in[3];
  const float* gq   = (const float*)d_in[4];
  const float* gk   = (const float*)d_in[5];
  const float* Wq   = (const float*)d_in[6];
  const float* Wkv  = (const float*)d_in[7];
  const float* Wout = (const float*)d_in[8];
  float* out = (float*)d_out;
  char* ws = (char*)d_ws;
  const size_t MB = (size_t)1 << 20;
  f16* qn    = (f16*)(ws + 0 * MB);    // 2 MB   [1024][1024]
  f16* Qm    = (f16*)(ws + 2 * MB);    // 2 MB   [1024][1024]
  f16* Om    = (f16*)(ws + 4 * MB);    // 2 MB   [1024][1024]
  f16* WqT   = (f16*)(ws + 6 * MB);    // 2 MB   [1024][1024]
  f16* WkvT  = (f16*)(ws + 8 * MB);    // 4 MB   [2048][1024]
  f16* WoutT = (f16*)(ws + 12 * MB);   // 2 MB   [1024][1024]
  f16* kv16  = (f16*)(ws + 14 * MB);   // 64 MB  [32768][1024]  (dead after gemm256)
  float* Opart = (float*)(ws + 14 * MB); // 16 MB [4][1024][1024] (reuses kv16)
  float* mlb   = (float*)(ws + 30 * MB); // 0.5 MB [4][1024][16][2]
  f16* KVp   = (f16*)(ws + 78 * MB);   // 128 MB [32768][2048]

  cast_f16_kernel<<<2048, 256, 0, stream>>>(kv, kv16, 8 * 4096 * 1024 / 4);
  transpose_cast_kernel<<<dim3(32, 32), 256, 0, stream>>>(Wq, WqT, 1024, 1024);
  transpose_cast_kernel<<<dim3(64, 32), 256, 0, stream>>>(Wkv, WkvT, 2048, 1024);
  transpose_cast_kernel<<<dim3(32, 32), 256, 0, stream>>>(Wout, WoutT, 1024, 1024);
  ln_kernel<<<1024, 256, 0, stream>>>(q, ln_w, qn);
  gemm128<1, 1><<<dim3(8, 8), 256, 0, stream>>>(qn, WqT, Qm, gq,
                                                1024, 1024, 1024, 1024, 1024, 1024);
  gemm256<<<1024, 512, 0, stream>>>(kv16, WkvT, KVp, gk, 1024,
                                    1024, 1024, 1024, 2048, 128, 8);
  attn_kernel<<<1024, 256, 0, stream>>>(Qm, KVp, mask, Opart, mlb);
  attn_merge_kernel<<<4096, 256, 0, stream>>>(Opart, mlb, Om);
  gemm128<0, 0><<<dim3(8, 8), 256, 0, stream>>>(Om, WoutT, out, nullptr,
                                                1024, 1024, 1024, 1024, 1024, 1024);
}

// Round 5
// 506.623 us; speedup vs baseline: 1.3362x; 1.0175x over previous
//
#include <hip/hip_runtime.h>
#include <cfloat>
#include <cstdint>

// ---------------------------------------------------------------------------
// AttentionPool: LN(q) @ Wq ; kv @ Wkv -> K,V ; per-head RMSNorm(Q,K) fused
// into GEMM epilogues; masked flash attention (split-KV, 4 chunks + merge);
// out @ Wout.  B=8, Nq=128, Nkv=4096, H=16, D=64. fp16 MFMA, fp32 accum.
// gemm256: 256x256 tile, BK=64, 2-buffer LDS [buf][op][kk][256][32],
// 8-phase schedule (m201 port): per phase {ds_read frags; stage half-tile;
// [vmcnt(6) at ph4/8]; barrier; setprio(1); 16 MFMA; setprio(0); barrier}.
// Race-freedom: stage slots >= last-read-phase+1 (WAR via barrier), residency
// via all-thread vmcnt(6)+barrier (RAW). Swizzle slot^=(r>>1)&3 (0 conflicts).
// ---------------------------------------------------------------------------

typedef _Float16 f16;
typedef _Float16 f16x8 __attribute__((ext_vector_type(8)));
typedef _Float16 f16x4 __attribute__((ext_vector_type(4)));
typedef float    f32x4 __attribute__((ext_vector_type(4)));

#define DEV __device__ __forceinline__

DEV f32x4 mfma16(f16x8 a, f16x8 b, f32x4 c) {
  return __builtin_amdgcn_mfma_f32_16x16x32_f16(a, b, c, 0, 0, 0);
}

DEV void gl_lds16(const void* g, void* l) {
  __builtin_amdgcn_global_load_lds(
      (const __attribute__((address_space(1))) uint32_t*)g,
      (__attribute__((address_space(3))) uint32_t*)l, 16, 0, 0);
}

// --------------------------- elementwise kernels ---------------------------

__global__ __launch_bounds__(256) void cast_f16_kernel(
    const float* __restrict__ src, f16* __restrict__ dst, int n4) {
  int stride = gridDim.x * 256;
  for (int i = blockIdx.x * 256 + threadIdx.x; i < n4; i += stride) {
    float4 v = ((const float4*)src)[i];
    f16x4 o = { (f16)v.x, (f16)v.y, (f16)v.z, (f16)v.w };
    ((f16x4*)dst)[i] = o;
  }
}

// all three weight transposes in one launch (fp32 [R][ld] -> f16 [C][ld'])
__global__ __launch_bounds__(256) void transpose_all_kernel(
    const float* __restrict__ Wq, const float* __restrict__ Wkv,
    const float* __restrict__ Wout,
    f16* __restrict__ WqT, f16* __restrict__ WkvT, f16* __restrict__ WoutT) {
  __shared__ float tile[32][33];
  int b = blockIdx.x;
  const float* src; f16* dst; int ldsrc, lddst, c0, r0;
  if (b < 1024)      { src = Wq;   dst = WqT;   ldsrc = 1024; lddst = 1024;
                       c0 = (b & 31) * 32;          r0 = (b >> 5) * 32; }
  else if (b < 3072) { int bb = b - 1024; src = Wkv; dst = WkvT; ldsrc = 2048;
                       lddst = 1024; c0 = (bb & 63) * 32; r0 = (bb >> 6) * 32; }
  else               { int bb = b - 3072; src = Wout; dst = WoutT; ldsrc = 1024;
                       lddst = 1024; c0 = (bb & 31) * 32; r0 = (bb >> 5) * 32; }
  int tx = threadIdx.x & 31, ty = threadIdx.x >> 5;  // 32 x 8
  #pragma unroll
  for (int i = 0; i < 4; ++i)
    tile[ty + i * 8][tx] = src[(long)(r0 + ty + i * 8) * ldsrc + c0 + tx];
  __syncthreads();
  #pragma unroll
  for (int i = 0; i < 4; ++i)
    dst[(long)(c0 + ty + i * 8) * lddst + r0 + tx] = (f16)tile[tx][ty + i * 8];
}

// LayerNorm over 1024, one block per row
__global__ __launch_bounds__(256) void ln_kernel(
    const float* __restrict__ q, const float* __restrict__ w, f16* __restrict__ qn) {
  int row = blockIdx.x, tid = threadIdx.x;
  float4 v = ((const float4*)(q + (long)row * 1024))[tid];
  float s1 = v.x + v.y + v.z + v.w;
  float s2 = v.x * v.x + v.y * v.y + v.z * v.z + v.w * v.w;
  #pragma unroll
  for (int off = 1; off < 64; off <<= 1) {
    s1 += __shfl_xor(s1, off);
    s2 += __shfl_xor(s2, off);
  }
  __shared__ float r1[4], r2[4];
  int wid = tid >> 6;
  if ((tid & 63) == 0) { r1[wid] = s1; r2[wid] = s2; }
  __syncthreads();
  s1 = r1[0] + r1[1] + r1[2] + r1[3];
  s2 = r2[0] + r2[1] + r2[2] + r2[3];
  float mu = s1 * (1.0f / 1024.0f);
  float var = s2 * (1.0f / 1024.0f) - mu * mu;
  float rstd = rsqrtf(var + 1e-5f);
  float4 wv = ((const float4*)w)[tid];
  f16x4 o = { (f16)((v.x - mu) * rstd * wv.x), (f16)((v.y - mu) * rstd * wv.y),
              (f16)((v.z - mu) * rstd * wv.z), (f16)((v.w - mu) * rstd * wv.w) };
  ((f16x4*)(qn + (long)row * 1024))[tid] = o;
}

// ------------------------ GEMM 128x128 (small mats) ------------------------
template <int OUT_F16, int NORM>
__global__ __launch_bounds__(256) void gemm128(
    const f16* __restrict__ A, const f16* __restrict__ BT, void* __restrict__ C,
    const float* __restrict__ gamma,
    int M, int N, int K, int lda, int ldb, int ldc) {
  __shared__ f16 tA[128 * 32];
  __shared__ f16 tB[128 * 32];
  const int tid = threadIdx.x, lane = tid & 63, wid = tid >> 6;
  const int wr = wid >> 1, wc = wid & 1;
  const int c = lane & 15, g = lane >> 4;
  const int m0 = blockIdx.y * 128, n0 = blockIdx.x * 128;
  f32x4 acc[4][4] = {};
  for (int k0 = 0; k0 < K; k0 += 32) {
    __syncthreads();
    #pragma unroll
    for (int ii = 0; ii < 2; ++ii) {
      int i = tid + ii * 256;
      gl_lds16(A + (long)(m0 + (i >> 2)) * lda + k0 + (i & 3) * 8, tA + i * 8);
    }
    #pragma unroll
    for (int ii = 0; ii < 2; ++ii) {
      int i = tid + ii * 256;
      gl_lds16(BT + (long)(n0 + (i >> 2)) * ldb + k0 + (i & 3) * 8, tB + i * 8);
    }
    __syncthreads();
    f16x8 af[4], bfr[4];
    #pragma unroll
    for (int mi = 0; mi < 4; ++mi)
      af[mi] = *(const f16x8*)&tA[(wr * 64 + mi * 16 + c) * 32 + g * 8];
    #pragma unroll
    for (int ni = 0; ni < 4; ++ni)
      bfr[ni] = *(const f16x8*)&tB[(wc * 64 + ni * 16 + c) * 32 + g * 8];
    #pragma unroll
    for (int mi = 0; mi < 4; ++mi)
      #pragma unroll
      for (int ni = 0; ni < 4; ++ni)
        acc[mi][ni] = mfma16(af[mi], bfr[ni], acc[mi][ni]);
  }
  float gam[4];
  if (NORM) {
    #pragma unroll
    for (int ni = 0; ni < 4; ++ni) gam[ni] = gamma[n0 + wc * 64 + ni * 16 + c];
    #pragma unroll
    for (int mi = 0; mi < 4; ++mi)
      #pragma unroll
      for (int j = 0; j < 4; ++j) {
        float s = 0.f;
        #pragma unroll
        for (int ni = 0; ni < 4; ++ni) { float x = acc[mi][ni][j]; s += x * x; }
        s += __shfl_xor(s, 1); s += __shfl_xor(s, 2);
        s += __shfl_xor(s, 4); s += __shfl_xor(s, 8);
        float sc = 8.0f / fmaxf(sqrtf(s), 1e-12f);
        #pragma unroll
        for (int ni = 0; ni < 4; ++ni) acc[mi][ni][j] *= sc * gam[ni];
      }
  }
  #pragma unroll
  for (int mi = 0; mi < 4; ++mi)
    #pragma unroll
    for (int ni = 0; ni < 4; ++ni)
      #pragma unroll
      for (int j = 0; j < 4; ++j) {
        int row = m0 + wr * 64 + mi * 16 + g * 4 + j;
        int col = n0 + wc * 64 + ni * 16 + c;
        if (OUT_F16) ((f16*)C)[(long)row * ldc + col] = (f16)acc[mi][ni][j];
        else        ((float*)C)[(long)row * ldc + col] = acc[mi][ni][j];
      }
}

// ---------------- GEMM 256x256, BK=64, 8-phase (KV projection) -------------
// LDS: lds[buf(2)][op(2: A,B)][kk(2)][row(256)][32 f16] = 128 KiB.
// Half-tile = (op, kk) region, staged by 2 gl_lds/thread. Stage stream (iter
// reading tiles t,t+1): ph1:(t+1).Ak1 | ph2:(t+2).Bk0 | ph3:(t+2).Ak0 |
// ph4:(t+2).Bk1 | ph5:(t+2).Ak1 | ph6:(t+3).Bk0 | ph7:(t+3).Ak0 | ph8:(t+3).Bk1.
// vmcnt(6) at ph4/ph8 (3 half-tiles in flight). All stage slots follow the
// staged region's last ds_read phase (WAR-safe via the inter-phase barrier);
// residency is vouched by vmcnt+barrier before first read (RAW-safe).
__global__ __launch_bounds__(512, 2) void gemm256(
    const f16* __restrict__ A, const f16* __restrict__ BT, f16* __restrict__ C,
    const float* __restrict__ gamma, int normLim,
    int K, int lda, int ldb, int ldc, int mtiles, int ntiles) {
  __shared__ f16 lds[2 * 32768];
  const int tid = threadIdx.x, lane = tid & 63, wid = tid >> 6;
  const int wr = wid >> 2, wc = wid & 3;  // 2 x 4 waves, per-wave C 128x64
  const int c = lane & 15, g = lane >> 4;
  const int nwg = mtiles * ntiles, cpx = nwg >> 3;
  const int bid = blockIdx.x;
  const int wg = (bid & 7) * cpx + (bid >> 3);
  const int n0 = (wg % ntiles) * 256;
  const long m0 = (long)(wg / ntiles) * 256;

  const int nkt = K >> 6;  // 64-wide K tiles
  // staging: thread covers flat 16B-slot f = tid + j*512 of a 256x32 region
  const int row1 = tid >> 2, row2 = (tid >> 2) + 128, sl = tid & 3;
  const int co1 = ((sl ^ ((row1 >> 1) & 3)) << 3);
  const int co2 = ((sl ^ ((row2 >> 1) & 3)) << 3);

  // per-thread fragment offsets (f16 units, within one [kk] region)
  int aoff[8], boff[4];
  #pragma unroll
  for (int mi = 0; mi < 8; ++mi) {
    int r = wr * 128 + mi * 16 + c;
    aoff[mi] = r * 32 + ((g ^ ((r >> 1) & 3)) << 3);
  }
  #pragma unroll
  for (int ni = 0; ni < 4; ++ni) {
    int r = wc * 64 + ni * 16 + c;
    boff[ni] = 16384 + r * 32 + ((g ^ ((r >> 1) & 3)) << 3);
  }

  f32x4 acc[8][4] = {};

#define STAGE_A(kk_, t_) do {                                                   \
    f16* dst = lds + ((t_) & 1) * 32768 + (kk_) * 8192;                          \
    int k0 = ((t_) << 6) + (kk_) * 32;                                           \
    gl_lds16(A + (m0 + row1) * lda + k0 + co1, dst + tid * 8);                   \
    gl_lds16(A + (m0 + row2) * lda + k0 + co2, dst + (tid + 512) * 8);           \
  } while (0)
#define STAGE_B(kk_, t_) do {                                                   \
    f16* dst = lds + ((t_) & 1) * 32768 + 16384 + (kk_) * 8192;                  \
    int k0 = ((t_) << 6) + (kk_) * 32;                                           \
    gl_lds16(BT + (long)(n0 + row1) * ldb + k0 + co1, dst + tid * 8);            \
    gl_lds16(BT + (long)(n0 + row2) * ldb + k0 + co2, dst + (tid + 512) * 8);    \
  } while (0)
#define LD_A(kk_, mh_, buf_)                                                    \
    _Pragma("unroll") for (int q = 0; q < 4; ++q)                               \
      af[q] = *(const f16x8*)&lds[(buf_) + (kk_) * 8192 + aoff[(mh_) * 4 + q]];
#define LD_B(kk_, buf_)                                                         \
    _Pragma("unroll") for (int q = 0; q < 4; ++q)                               \
      bf[q] = *(const f16x8*)&lds[(buf_) + (kk_) * 8192 + boff[q]];
#define MM(mh_)                                                                 \
    __builtin_amdgcn_s_setprio(1);                                              \
    _Pragma("unroll") for (int q = 0; q < 4; ++q)                               \
      _Pragma("unroll") for (int ni = 0; ni < 4; ++ni)                          \
        acc[(mh_) * 4 + q][ni] = mfma16(af[q], bf[ni], acc[(mh_) * 4 + q][ni]); \
    __builtin_amdgcn_s_setprio(0);
#define BAR __builtin_amdgcn_s_barrier()
#define VM6 asm volatile("s_waitcnt vmcnt(6)" ::: "memory")
#define VM0 asm volatile("s_waitcnt vmcnt(0)" ::: "memory")

  // prologue stream: t0.{Bk0,Ak0,Bk1,Ak1}, t1.{Bk0,Ak0,Bk1}; drain to tile0
  STAGE_B(0, 0); STAGE_A(0, 0); STAGE_B(1, 0); STAGE_A(1, 0);
  STAGE_B(0, 1); STAGE_A(0, 1); STAGE_B(1, 1);
  VM6; BAR;

  const int niter = nkt >> 1;
  for (int it = 0; it < niter; ++it) {
    const int t = it << 1;
    const bool p2 = (t + 2) < nkt, p3 = (t + 3) < nkt;
    f16x8 af[4], bf[4];
    // ph1: MFMA(kk0, mlow) of tile t (buf0)
    LD_B(0, 0); LD_A(0, 0, 0);
    STAGE_A(1, t + 1);
    BAR; MM(0); BAR;
    // ph2: MFMA(kk0, mhigh)
    LD_A(0, 1, 0);
    if (p2) STAGE_B(0, t + 2);
    BAR; MM(1); BAR;
    // ph3: MFMA(kk1, mlow)
    LD_B(1, 0); LD_A(1, 0, 0);
    if (p2) STAGE_A(0, t + 2);
    BAR; MM(0); BAR;
    // ph4: MFMA(kk1, mhigh) + counted wait
    LD_A(1, 1, 0);
    if (p2) { STAGE_B(1, t + 2); VM6; } else { VM0; }
    BAR; MM(1); BAR;
    // ph5: MFMA(kk0, mlow) of tile t+1 (buf1)
    LD_B(0, 32768); LD_A(0, 0, 32768);
    if (p2) STAGE_A(1, t + 2);
    BAR; MM(0); BAR;
    // ph6: MFMA(kk0, mhigh)
    LD_A(0, 1, 32768);
    if (p3) STAGE_B(0, t + 3);
    BAR; MM(1); BAR;
    // ph7: MFMA(kk1, mlow)
    LD_B(1, 32768); LD_A(1, 0, 32768);
    if (p3) STAGE_A(0, t + 3);
    BAR; MM(0); BAR;
    // ph8: MFMA(kk1, mhigh) + counted wait
    LD_A(1, 1, 32768);
    if (p3) { STAGE_B(1, t + 3); VM6; } else { VM0; }
    BAR; MM(1); BAR;
  }
#undef STAGE_A
#undef STAGE_B
#undef LD_A
#undef LD_B
#undef MM
#undef BAR
#undef VM6
#undef VM0

  // epilogue: optional fused per-head RMSNorm (wave spans exactly one head)
  const int colbase = n0 + wc * 64;
  if (colbase < normLim) {
    float gam[4];
    #pragma unroll
    for (int ni = 0; ni < 4; ++ni) gam[ni] = gamma[colbase + ni * 16 + c];
    #pragma unroll
    for (int mi = 0; mi < 8; ++mi)
      #pragma unroll
      for (int j = 0; j < 4; ++j) {
        float s = 0.f;
        #pragma unroll
        for (int ni = 0; ni < 4; ++ni) { float x = acc[mi][ni][j]; s += x * x; }
        s += __shfl_xor(s, 1); s += __shfl_xor(s, 2);
        s += __shfl_xor(s, 4); s += __shfl_xor(s, 8);
        float sc = 8.0f / fmaxf(sqrtf(s), 1e-12f);
        #pragma unroll
        for (int ni = 0; ni < 4; ++ni) acc[mi][ni][j] *= sc * gam[ni];
      }
  }
  #pragma unroll
  for (int mi = 0; mi < 8; ++mi)
    #pragma unroll
    for (int j = 0; j < 4; ++j) {
      long row = m0 + wr * 128 + mi * 16 + g * 4 + j;
      #pragma unroll
      for (int ni = 0; ni < 4; ++ni)
        C[row * ldc + colbase + ni * 16 + c] = (f16)acc[mi][ni][j];
    }
}

// ------------------- flash attention, split-KV (4 chunks) ------------------
__global__ __launch_bounds__(256) void attn_kernel(
    const f16* __restrict__ Q, const f16* __restrict__ KV,
    const int* __restrict__ mask, float* __restrict__ Opart,
    float* __restrict__ ml) {
  __shared__ f16 Kt[64 * 64];       // XOR-swizzled [kv][64]
  __shared__ f16 Vt[64 * 72];       // transposed [d][kv], stride 72
  __shared__ f16 Pl[4 * 16 * 72];   // per-wave P [16 q][64 kv], stride 72
  const int blk = blockIdx.x;
  const int chunk = blk >> 8, sub = blk & 255;
  const int half = sub & 1, h = (sub >> 1) & 15, b = sub >> 5;
  const int tid = threadIdx.x, lane = tid & 63, wid = tid >> 6;
  const int c = lane & 15, g = lane >> 4;

  const int qrow = b * 128 + half * 64 + wid * 16 + c;
  f16x8 qa[2];
  #pragma unroll
  for (int kk = 0; kk < 2; ++kk)
    qa[kk] = *(const f16x8*)&Q[(long)qrow * 1024 + h * 64 + kk * 32 + g * 8];

  float m_[4], l_[4];
  f32x4 o_[4];
  #pragma unroll
  for (int j = 0; j < 4; ++j) { m_[j] = -FLT_MAX; l_[j] = 0.f; }
  #pragma unroll
  for (int ni = 0; ni < 4; ++ni) o_[ni] = (f32x4){0.f, 0.f, 0.f, 0.f};

  const long kvbase = (long)b * 4096 * 2048;
  f16* Pw = Pl + wid * 16 * 72;

  for (int kt = chunk * 16; kt < chunk * 16 + 16; ++kt) {
    __syncthreads();
    #pragma unroll
    for (int ii = 0; ii < 2; ++ii) {
      int i = tid + ii * 256;
      int r = i >> 3, s = i & 7;
      gl_lds16(KV + kvbase + (long)(kt * 64 + r) * 2048 + h * 64 + ((s ^ (r & 7)) * 8),
               Kt + i * 8);
    }
    #pragma unroll
    for (int ii = 0; ii < 2; ++ii) {
      int i = tid + ii * 256;
      int kv = i & 63, d0 = (i >> 6) * 8;
      f16x8 v = *(const f16x8*)&KV[kvbase + (long)(kt * 64 + kv) * 2048 + 1024 + h * 64 + d0];
      #pragma unroll
      for (int j = 0; j < 8; ++j) Vt[(d0 + j) * 72 + kv] = v[j];
    }
    __syncthreads();

    f32x4 s4[4];
    #pragma unroll
    for (int ni = 0; ni < 4; ++ni) {
      s4[ni] = (f32x4){0.f, 0.f, 0.f, 0.f};
      int kvr = ni * 16 + c;
      #pragma unroll
      for (int kk = 0; kk < 2; ++kk) {
        int slot = (kk * 4 + g) ^ (kvr & 7);
        f16x8 kb = *(const f16x8*)&Kt[kvr * 64 + slot * 8];
        s4[ni] = mfma16(qa[kk], kb, s4[ni]);
      }
    }

    int msk[4];
    #pragma unroll
    for (int ni = 0; ni < 4; ++ni) {
      msk[ni] = mask[b * 4096 + kt * 64 + ni * 16 + c];
      if (!msk[ni]) s4[ni] = (f32x4){-FLT_MAX, -FLT_MAX, -FLT_MAX, -FLT_MAX};
    }

    float mnew[4], alpha[4], psum[4];
    #pragma unroll
    for (int j = 0; j < 4; ++j) {
      float v = fmaxf(fmaxf(s4[0][j], s4[1][j]), fmaxf(s4[2][j], s4[3][j]));
      v = fmaxf(v, __shfl_xor(v, 1));
      v = fmaxf(v, __shfl_xor(v, 2));
      v = fmaxf(v, __shfl_xor(v, 4));
      v = fmaxf(v, __shfl_xor(v, 8));
      mnew[j] = fmaxf(m_[j], v);
      alpha[j] = __expf(m_[j] - mnew[j]);
      m_[j] = mnew[j];
      psum[j] = 0.f;
    }
    f16 pb[4][4];
    #pragma unroll
    for (int ni = 0; ni < 4; ++ni)
      #pragma unroll
      for (int j = 0; j < 4; ++j) {
        float p = msk[ni] ? __expf(s4[ni][j] - mnew[j]) : 0.0f;
        psum[j] += p;
        pb[ni][j] = (f16)p;
      }
    #pragma unroll
    for (int j = 0; j < 4; ++j) {
      float ps = psum[j];
      ps += __shfl_xor(ps, 1);
      ps += __shfl_xor(ps, 2);
      ps += __shfl_xor(ps, 4);
      ps += __shfl_xor(ps, 8);
      l_[j] = alpha[j] * l_[j] + ps;
    }
    #pragma unroll
    for (int ni = 0; ni < 4; ++ni)
      #pragma unroll
      for (int j = 0; j < 4; ++j)
        Pw[(g * 4 + j) * 72 + ni * 16 + c] = pb[ni][j];
    #pragma unroll
    for (int ni = 0; ni < 4; ++ni)
      #pragma unroll
      for (int j = 0; j < 4; ++j)
        o_[ni][j] *= alpha[j];
    f16x8 pa[2];
    #pragma unroll
    for (int kk = 0; kk < 2; ++kk)
      pa[kk] = *(const f16x8*)&Pw[c * 72 + kk * 32 + g * 8];
    #pragma unroll
    for (int ni = 0; ni < 4; ++ni)
      #pragma unroll
      for (int kk = 0; kk < 2; ++kk) {
        f16x8 vb = *(const f16x8*)&Vt[(ni * 16 + c) * 72 + kk * 32 + g * 8];
        o_[ni] = mfma16(pa[kk], vb, o_[ni]);
      }
  }

  #pragma unroll
  for (int j = 0; j < 4; ++j) {
    int row = b * 128 + half * 64 + wid * 16 + g * 4 + j;
    #pragma unroll
    for (int ni = 0; ni < 4; ++ni)
      Opart[((long)chunk * 1024 + row) * 1024 + h * 64 + ni * 16 + c] = o_[ni][j];
    if (c == 0) {
      long u = (((long)chunk * 1024 + row) * 16 + h) * 2;
      ml[u] = m_[j];
      ml[u + 1] = l_[j];
    }
  }
}

// merge 4 partials: one wave per (row, head)
__global__ __launch_bounds__(256) void attn_merge_kernel(
    const float* __restrict__ Opart, const float* __restrict__ ml,
    f16* __restrict__ Om) {
  int unit = blockIdx.x * 4 + (threadIdx.x >> 6);
  int lane = threadIdx.x & 63;
  int row = unit >> 4, h = unit & 15;
  float mc[4], lc[4], M = -FLT_MAX;
  #pragma unroll
  for (int cI = 0; cI < 4; ++cI) {
    long u = (((long)cI * 1024 + row) * 16 + h) * 2;
    mc[cI] = ml[u]; lc[cI] = ml[u + 1];
    M = fmaxf(M, mc[cI]);
  }
  float L = 0.f, o = 0.f;
  #pragma unroll
  for (int cI = 0; cI < 4; ++cI) {
    float w = __expf(mc[cI] - M);
    L += lc[cI] * w;
    o += Opart[((long)cI * 1024 + row) * 1024 + h * 64 + lane] * w;
  }
  Om[(long)row * 1024 + h * 64 + lane] = (f16)(o / fmaxf(L, 1e-30f));
}

// ------------------------------- launcher ----------------------------------

extern "C" void kernel_launch(void* const* d_in, const int* in_sizes, int n_in,
                              void* d_out, int out_size, void* d_ws, size_t ws_size,
                              hipStream_t stream) {
  const float* q    = (const float*)d_in[0];
  const float* kv   = (const float*)d_in[1];
  const int*   mask = (const int*)d_in[2];
  const float* ln_w = (const float*)d_in[3];
  const float* gq   = (const float*)d_in[4];
  const float* gk   = (const float*)d_in[5];
  const float* Wq   = (const float*)d_in[6];
  const float* Wkv  = (const float*)d_in[7];
  const float* Wout = (const float*)d_in[8];
  float* out = (float*)d_out;
  char* ws = (char*)d_ws;
  const size_t MB = (size_t)1 << 20;
  f16* qn    = (f16*)(ws + 0 * MB);    // 2 MB   [1024][1024]
  f16* Qm    = (f16*)(ws + 2 * MB);    // 2 MB   [1024][1024]
  f16* Om    = (f16*)(ws + 4 * MB);    // 2 MB   [1024][1024]
  f16* WqT   = (f16*)(ws + 6 * MB);    // 2 MB   [1024][1024]
  f16* WkvT  = (f16*)(ws + 8 * MB);    // 4 MB   [2048][1024]
  f16* WoutT = (f16*)(ws + 12 * MB);   // 2 MB   [1024][1024]
  f16* kv16  = (f16*)(ws + 14 * MB);   // 64 MB  [32768][1024]  (dead after gemm256)
  float* Opart = (float*)(ws + 14 * MB); // 16 MB [4][1024][1024] (reuses kv16)
  float* mlb   = (float*)(ws + 30 * MB); // 0.5 MB [4][1024][16][2]
  f16* KVp   = (f16*)(ws + 78 * MB);   // 128 MB [32768][2048]

  cast_f16_kernel<<<2048, 256, 0, stream>>>(kv, kv16, 8 * 4096 * 1024 / 4);
  transpose_all_kernel<<<4096, 256, 0, stream>>>(Wq, Wkv, Wout, WqT, WkvT, WoutT);
  ln_kernel<<<1024, 256, 0, stream>>>(q, ln_w, qn);
  gemm128<1, 1><<<dim3(8, 8), 256, 0, stream>>>(qn, WqT, Qm, gq,
                                                1024, 1024, 1024, 1024, 1024, 1024);
  gemm256<<<1024, 512, 0, stream>>>(kv16, WkvT, KVp, gk, 1024,
                                    1024, 1024, 1024, 2048, 128, 8);
  attn_kernel<<<1024, 256, 0, stream>>>(Qm, KVp, mask, Opart, mlb);
  attn_merge_kernel<<<4096, 256, 0, stream>>>(Opart, mlb, Om);
  gemm128<0, 0><<<dim3(8, 8), 256, 0, stream>>>(Om, WoutT, out, nullptr,
                                                1024, 1024, 1024, 1024, 1024, 1024);
}